// Round 6
// baseline (3050.977 us; speedup 1.0000x reference)
//
#include <hip/hip_runtime.h>

// DISCO block: conv(11x11, disk support) -> InstanceNorm -> LeakyReLU, twice.
// B=4, C=32, H=W=256. fp32 (no fp32 MFMA on CDNA4 -> VALU conv).
//
// R5 restructure after first measured baseline (1917us; conv 1010us each,
// VALUBusy 44%, Occ 23.8%):
//  - weights moved LDS->global/L2 (wave-uniform addr, 2 float4 per tap)
//  - 256-thr blocks, thread = 4px x 8oc, 1024 blocks = 4 blocks/CU
//    -> 16 waves/CU (occupancy 2x)
//  - per-(ci,row) pixel row cached in registers via 3-5 ds_read_b128,
//    reused across all taps in the row (LDS instr ~7x down)

#define HALO  5
#define TSX   16           // output tile x
#define TSY   16           // output tile y
#define LDSX  36           // staged row width: 8(left halo) + 16 + 12
#define LDSY  26           // 16 + 2*5
#define ICC   8            // input channels per LDS chunk (29.25 KB)

// disk row extents: |ddx| <= floor(sqrt(26 - ddy^2)), ddy = kdy-5
__device__ __constant__ int KMIN_[11] = {4, 2, 1, 1, 0, 0, 0, 1, 1, 2, 4};
__device__ __constant__ int KMAX_[11] = {6, 8, 9, 9, 10, 10, 10, 9, 9, 8, 6};
// (indexed only by unrolled compile-time kdy -> folds to constants)

// ---------------------------------------------------------------------------
// Kernel-builder: PSI basis (fp64, matches numpy) -> dense kernels in layout
// kern[ic][og][tap][8]  (og = oc>>3), so one tap = 2 contiguous float4.
// ---------------------------------------------------------------------------
__global__ void build_kern_kernel(const float* __restrict__ w1,
                                  const float* __restrict__ w2,
                                  float* __restrict__ kern1,
                                  float* __restrict__ kern2) {
  __shared__ float psi[36 * 121];
  const int blk   = blockIdx.x;   // 0..63
  const int layer = blk >> 5;
  const int i     = blk & 31;
  const int tid   = threadIdx.x;  // 128 threads
  const double PI     = 3.141592653589793;
  const double TWO_PI = 6.283185307179586;
  for (int t = tid; t < 121; t += 128) {
    const int ky = t / 11, kx = t % 11;
    const double y = (ky - 5) / 255.0;
    const double x = (kx - 5) / 255.0;
    const double r = sqrt(x * x + y * y);
    double phi = atan2(y, x);
    if (phi < 0.0) phi += TWO_PI;
    const double inside = (r <= 0.02) ? 1.0 : 0.0;
    const double dr   = 0.02 / 5.0;
    const double dphi = TWO_PI / 7.0;
    psi[t] = (float)(fmax(0.0, 1.0 - r / dr) * inside);
    for (int j = 1; j < 6; ++j) {
      const double rad = fmax(0.0, 1.0 - fabs(r - j * dr) / dr) * inside;
      for (int k = 0; k < 7; ++k) {
        double d = fmod(phi - k * dphi + PI, TWO_PI);
        if (d < 0.0) d += TWO_PI;
        d = fabs(d - PI);
        const double ang = fmax(0.0, 1.0 - d / dphi);
        psi[(1 + (j - 1) * 7 + k) * 121 + t] = (float)(rad * ang);
      }
    }
  }
  __syncthreads();
  const float* w  = layer ? w2 : w1;
  float*       ko = layer ? kern2 : kern1;
  for (int idx = tid; idx < 121 * 32; idx += 128) {
    const int t  = idx >> 5;
    const int o  = idx & 31;
    const float* wp = w + (o * 32 + i) * 36;  // w[o][i][k], K=36
    float s = 0.f;
#pragma unroll
    for (int k = 0; k < 36; ++k) s = fmaf(wp[k], psi[k * 121 + t], s);
    // layout: [ic=i][og=o>>3][tap=t][j=o&7]
    ko[((size_t)(i * 4 + (o >> 3)) * 121 + t) * 8 + (o & 7)] = s;
  }
}

// ---------------------------------------------------------------------------
// Direct conv. Block: 16x16 px, all 32 oc, one batch. 256 threads:
//   xg = tid&3 (4 px each), y = (tid>>2)&15, og = tid>>6 (8 oc, wave-uniform).
// Pixel tile (ICC channels, haloed) in LDS; weights straight from L2.
// Per (ci,kdy): row -> registers (b128), taps of the row reuse it.
// ---------------------------------------------------------------------------
template <bool NORM_IN>
__global__ __launch_bounds__(256, 4)
void conv_kernel(const float* __restrict__ in, const float* __restrict__ kern,
                 float* __restrict__ out, const float2* __restrict__ stats) {
  __shared__ float tile[ICC][LDSY][LDSX];  // 8*26*36*4B = 29.25 KB
  const int tid = threadIdx.x;
  const int xg  = tid & 3;
  const int y   = (tid >> 2) & 15;
  const int og  = tid >> 6;          // wave index == oc-group
  const int bx0 = blockIdx.x * TSX;
  const int by0 = blockIdx.y * TSY;
  const int b   = blockIdx.z;

  float acc[32];                     // [oc 8][px 4]
#pragma unroll
  for (int j = 0; j < 32; ++j) acc[j] = 0.f;

  const float4* k4 = reinterpret_cast<const float4*>(kern);

  for (int ic0 = 0; ic0 < 32; ic0 += ICC) {
    __syncthreads();
    // ---- stage ICC channels of the haloed tile ----
    for (int idx = tid; idx < ICC * LDSY * LDSX; idx += 256) {
      const int ci  = idx / (LDSY * LDSX);
      const int rem = idx - ci * (LDSY * LDSX);
      const int yy  = rem / LDSX;
      const int xx  = rem - yy * LDSX;
      const int gy  = by0 + yy - HALO;
      const int gx  = bx0 + xx - 8;     // left halo 8 keeps b128 alignment
      float v = 0.f;
      if ((unsigned)gy < 256u && (unsigned)gx < 256u) {
        v = in[(((b << 5) + ic0 + ci) << 16) + (gy << 8) + gx];
        if (NORM_IN) {
          const float2 st = stats[(b << 5) + ic0 + ci];
          v = (v - st.x) * st.y;
          v = v < 0.f ? 0.2f * v : v;
        }
      }
      (&tile[0][0][0])[idx] = v;
    }
    __syncthreads();
    // ---- accumulate ----
    for (int ci = 0; ci < ICC; ++ci) {
      // weight base for (ic, og): float4 index = ((ic*4+og)*121 + tap)*2
      const float4* kb = k4 + (size_t)((ic0 + ci) * 4 + og) * 242;
#pragma unroll
      for (int kdy = 0; kdy < 11; ++kdy) {
        const int kmin = KMIN_[kdy];      // compile-time after unroll
        const int kmax = KMAX_[kdy];
        const int blo  = (3 + kmin) >> 2;
        const int bhi  = (6 + kmax) >> 2;
        // row cache: r[j] = tile[ci][y+kdy][4*xg + j]
        const float* rowp = &tile[ci][y + kdy][4 * xg];
        float r[20];
#pragma unroll
        for (int bk = 0; bk < 5; ++bk) {
          if (bk >= blo && bk <= bhi) {
            const float4 q = *reinterpret_cast<const float4*>(rowp + 4 * bk);
            r[4 * bk + 0] = q.x; r[4 * bk + 1] = q.y;
            r[4 * bk + 2] = q.z; r[4 * bk + 3] = q.w;
          }
        }
#pragma unroll
        for (int kdx = 0; kdx < 11; ++kdx) {
          if (kdx < kmin || kdx > kmax) continue;   // folds at compile time
          const float4 wa = kb[(kdy * 11 + kdx) * 2];
          const float4 wb = kb[(kdy * 11 + kdx) * 2 + 1];
#pragma unroll
          for (int p = 0; p < 4; ++p) {
            const float v = r[3 + kdx + p];
            acc[0 * 4 + p] = fmaf(wa.x, v, acc[0 * 4 + p]);
            acc[1 * 4 + p] = fmaf(wa.y, v, acc[1 * 4 + p]);
            acc[2 * 4 + p] = fmaf(wa.z, v, acc[2 * 4 + p]);
            acc[3 * 4 + p] = fmaf(wa.w, v, acc[3 * 4 + p]);
            acc[4 * 4 + p] = fmaf(wb.x, v, acc[4 * 4 + p]);
            acc[5 * 4 + p] = fmaf(wb.y, v, acc[5 * 4 + p]);
            acc[6 * 4 + p] = fmaf(wb.z, v, acc[6 * 4 + p]);
            acc[7 * 4 + p] = fmaf(wb.w, v, acc[7 * 4 + p]);
          }
        }
      }
    }
  }
  // ---- write raw (pre-norm) conv output: 8 oc x 4 px per thread ----
  const int gy = by0 + y;
  const int gx = bx0 + 4 * xg;
#pragma unroll
  for (int k = 0; k < 8; ++k) {
    const int o = og * 8 + k;
    *reinterpret_cast<float4*>(&out[(((b << 5) + o) << 16) + (gy << 8) + gx]) =
        make_float4(acc[k * 4 + 0], acc[k * 4 + 1],
                    acc[k * 4 + 2], acc[k * 4 + 3]);
  }
}

// ---------------------------------------------------------------------------
// Per-(b,c) plane mean / rstd. One block per plane, no atomics.
// ---------------------------------------------------------------------------
__global__ void stats_kernel(const float* __restrict__ y,
                             float2* __restrict__ stats) {
  const int bo  = blockIdx.x;            // 0..127
  const int tid = threadIdx.x;           // 256 threads
  const float4* p = reinterpret_cast<const float4*>(y + (size_t)bo * 65536);
  float s = 0.f, q = 0.f;
  for (int i = tid; i < 16384; i += 256) {
    const float4 v = p[i];
    s += v.x + v.y + v.z + v.w;
    q += v.x * v.x + v.y * v.y + v.z * v.z + v.w * v.w;
  }
#pragma unroll
  for (int off = 32; off > 0; off >>= 1) {
    s += __shfl_down(s, off);
    q += __shfl_down(q, off);
  }
  __shared__ float sh[8];
  const int lane = tid & 63, wid = tid >> 6;
  if (lane == 0) { sh[wid] = s; sh[4 + wid] = q; }
  __syncthreads();
  if (tid == 0) {
    const float S = sh[0] + sh[1] + sh[2] + sh[3];
    const float Q = sh[4] + sh[5] + sh[6] + sh[7];
    const float mean = S * (1.f / 65536.f);
    const float var  = Q * (1.f / 65536.f) - mean * mean;
    stats[bo] = make_float2(mean, __frsqrt_rn(var + 1e-5f));
  }
}

// ---------------------------------------------------------------------------
// Final in-place InstanceNorm + LeakyReLU on d_out.
// ---------------------------------------------------------------------------
__global__ void finalize_kernel(float* __restrict__ y,
                                const float2* __restrict__ stats) {
  const int n4 = (4 * 32 * 65536) / 4;  // 2097152 float4s
  float4* p = reinterpret_cast<float4*>(y);
  for (int i = blockIdx.x * blockDim.x + threadIdx.x; i < n4;
       i += gridDim.x * blockDim.x) {
    float4 v = p[i];
    const float2 st = stats[i >> 14];   // 16384 float4 per plane
    float t;
    t = (v.x - st.x) * st.y; v.x = t < 0.f ? 0.2f * t : t;
    t = (v.y - st.x) * st.y; v.y = t < 0.f ? 0.2f * t : t;
    t = (v.z - st.x) * st.y; v.z = t < 0.f ? 0.2f * t : t;
    t = (v.w - st.x) * st.y; v.w = t < 0.f ? 0.2f * t : t;
    p[i] = v;
  }
}

// ---------------------------------------------------------------------------
extern "C" void kernel_launch(void* const* d_in, const int* in_sizes, int n_in,
                              void* d_out, int out_size, void* d_ws,
                              size_t ws_size, hipStream_t stream) {
  const float* image = (const float*)d_in[0];
  const float* w1    = (const float*)d_in[1];
  const float* w2    = (const float*)d_in[2];
  float* out = (float*)d_out;
  float* ws  = (float*)d_ws;

  // ws layout (floats): kern1[123904] kern2[123904] y1[8388608] stats[512]
  float*  kern1  = ws;
  float*  kern2  = ws + 123904;
  float*  y1     = ws + 247808;
  float2* stats1 = (float2*)(ws + 247808 + 8388608);
  float2* stats2 = stats1 + 128;

  build_kern_kernel<<<64, 128, 0, stream>>>(w1, w2, kern1, kern2);

  dim3 cgrid(16, 16, 4);  // 16x16 tiles, batch; 1024 blocks = 4/CU
  conv_kernel<false><<<cgrid, 256, 0, stream>>>(image, kern1, y1, nullptr);
  stats_kernel<<<128, 256, 0, stream>>>(y1, stats1);
  conv_kernel<true><<<cgrid, 256, 0, stream>>>(y1, kern2, out, stats1);
  stats_kernel<<<128, 256, 0, stream>>>(out, stats2);
  finalize_kernel<<<2048, 256, 0, stream>>>(out, stats2);
}

// Round 7
// 1373.605 us; speedup vs baseline: 2.2211x; 2.2211x over previous
//
#include <hip/hip_runtime.h>

// DISCO block: conv(11x11, disk support) -> InstanceNorm -> LeakyReLU, twice.
// B=4, C=32, H=W=256. fp32 (no fp32 MFMA on CDNA4 -> VALU conv).
//
// R6: revert to R4 skeleton (odd LDS stride 43, literal disk-test folding),
// fix its two measured bottlenecks:
//  - weights OFF the LDS pipe: per-tap 32 uniform contiguous floats, no tid
//    in the address -> s_load_dwordx16 on the scalar pipe (R4 spent ~56% of
//    conv time issuing 8x ds_read_b128 weight broadcasts per tap)
//  - occupancy 2 waves/SIMD -> 4: tile 32x16, 512 thr, 1px x 32oc/thread,
//    512 blocks = 2/CU; LDS 35KB (tile only)

#define HALO 5
#define TSX  32            // output tile x
#define TSY  16            // output tile y
#define TW   42            // TSX + 2*HALO
#define LDSY 26            // TSY + 2*HALO
#define TWP  43            // padded LDS row stride (odd -> worst 2-way alias, free)
#define ICC  8             // input channels per LDS chunk (8*26*43*4B = 35 KB)

// ---------------------------------------------------------------------------
// Kernel-builder: PSI basis (fp64, matches numpy) -> dense kernels in layout
// kern[ic][tap][32oc] (one tap = 128B contiguous, 128B-aligned).
// ---------------------------------------------------------------------------
__global__ void build_kern_kernel(const float* __restrict__ w1,
                                  const float* __restrict__ w2,
                                  float* __restrict__ kern1,
                                  float* __restrict__ kern2) {
  __shared__ float psi[36 * 121];
  const int blk   = blockIdx.x;   // 0..63
  const int layer = blk >> 5;
  const int i     = blk & 31;
  const int tid   = threadIdx.x;  // 128 threads
  const double PI     = 3.141592653589793;
  const double TWO_PI = 6.283185307179586;
  for (int t = tid; t < 121; t += 128) {
    const int ky = t / 11, kx = t % 11;
    const double y = (ky - 5) / 255.0;
    const double x = (kx - 5) / 255.0;
    const double r = sqrt(x * x + y * y);
    double phi = atan2(y, x);
    if (phi < 0.0) phi += TWO_PI;
    const double inside = (r <= 0.02) ? 1.0 : 0.0;
    const double dr   = 0.02 / 5.0;
    const double dphi = TWO_PI / 7.0;
    psi[t] = (float)(fmax(0.0, 1.0 - r / dr) * inside);
    for (int j = 1; j < 6; ++j) {
      const double rad = fmax(0.0, 1.0 - fabs(r - j * dr) / dr) * inside;
      for (int k = 0; k < 7; ++k) {
        double d = fmod(phi - k * dphi + PI, TWO_PI);
        if (d < 0.0) d += TWO_PI;
        d = fabs(d - PI);
        const double ang = fmax(0.0, 1.0 - d / dphi);
        psi[(1 + (j - 1) * 7 + k) * 121 + t] = (float)(rad * ang);
      }
    }
  }
  __syncthreads();
  const float* w  = layer ? w2 : w1;
  float*       ko = (layer ? kern2 : kern1) + i * (121 * 32);
  for (int idx = tid; idx < 121 * 32; idx += 128) {
    const int t = idx >> 5;
    const int o = idx & 31;
    const float* wp = w + (o * 32 + i) * 36;  // w[o][i][k], K=36
    float s = 0.f;
#pragma unroll
    for (int k = 0; k < 36; ++k) s = fmaf(wp[k], psi[k * 121 + t], s);
    ko[t * 32 + o] = s;
  }
}

// ---------------------------------------------------------------------------
// Direct conv. Block: 32x16 px, all 32 oc, one batch. 512 threads:
//   x = tid&31, y = tid>>5. Thread = 1 px x 32 oc (acc[32]).
// Pixel tile in LDS (stride 43); weights read via uniform address ->
// s_load_dwordx16 x2 per tap (scalar pipe), FMAs consume SGPRs directly.
// Disk test is literal integer arithmetic on unrolled loop vars -> folds.
// ---------------------------------------------------------------------------
template <bool NORM_IN>
__global__ __launch_bounds__(512, 4)
void conv_kernel(const float* __restrict__ in, const float* __restrict__ kern,
                 float* __restrict__ out, const float2* __restrict__ stats) {
  __shared__ float tile[ICC][LDSY * TWP];  // 8*26*43*4B = 35 KB
  const int tid = threadIdx.x;
  const int x   = tid & 31;
  const int y   = tid >> 5;          // 0..15
  const int bx0 = blockIdx.x * TSX;
  const int by0 = blockIdx.y * TSY;
  const int b   = blockIdx.z;

  float acc[32];
#pragma unroll
  for (int j = 0; j < 32; ++j) acc[j] = 0.f;

  for (int ic0 = 0; ic0 < 32; ic0 += ICC) {
    __syncthreads();
    // ---- stage ICC channels of the haloed tile ----
    for (int idx = tid; idx < ICC * LDSY * TW; idx += 512) {
      const int ci  = idx / (LDSY * TW);
      const int rem = idx - ci * (LDSY * TW);
      const int yy  = rem / TW;
      const int xx  = rem - yy * TW;
      const int gy  = by0 + yy - HALO;
      const int gx  = bx0 + xx - HALO;
      float v = 0.f;
      if ((unsigned)gy < 256u && (unsigned)gx < 256u) {
        v = in[(((b << 5) + ic0 + ci) << 16) + (gy << 8) + gx];
        if (NORM_IN) {
          const float2 st = stats[(b << 5) + ic0 + ci];
          v = (v - st.x) * st.y;
          v = v < 0.f ? 0.2f * v : v;
        }
      }
      tile[ci][yy * TWP + xx] = v;
    }
    __syncthreads();
    // ---- accumulate ----
    for (int ci = 0; ci < ICC; ++ci) {
      const float* tb = &tile[ci][y * TWP + x];
      const float* kb = kern + (size_t)(ic0 + ci) * (121 * 32);  // uniform
#pragma unroll
      for (int kdy = 0; kdy < 11; ++kdy) {
#pragma unroll
        for (int kdx = 0; kdx < 11; ++kdx) {
          if ((kdy - 5) * (kdy - 5) + (kdx - 5) * (kdx - 5) > 26)
            continue;  // outside disk: kern==0 (folds at compile time)
          const float v = tb[kdy * TWP + kdx];          // 1 ds_read_b32
          const float* wp = kb + (kdy * 11 + kdx) * 32; // uniform -> s_load
#pragma unroll
          for (int o = 0; o < 32; ++o)
            acc[o] = fmaf(wp[o], v, acc[o]);            // v_fmac, SGPR src
        }
      }
    }
  }
  // ---- write raw (pre-norm) conv output: 32 oc, 1 px per thread ----
  const int gy = by0 + y;
  const int gx = bx0 + x;
#pragma unroll
  for (int o = 0; o < 32; ++o)
    out[(((b << 5) + o) << 16) + (gy << 8) + gx] = acc[o];
}

// ---------------------------------------------------------------------------
// Per-(b,c) plane mean / rstd. One block per plane, no atomics.
// ---------------------------------------------------------------------------
__global__ void stats_kernel(const float* __restrict__ y,
                             float2* __restrict__ stats) {
  const int bo  = blockIdx.x;            // 0..127
  const int tid = threadIdx.x;           // 256 threads
  const float4* p = reinterpret_cast<const float4*>(y + (size_t)bo * 65536);
  float s = 0.f, q = 0.f;
  for (int i = tid; i < 16384; i += 256) {
    const float4 v = p[i];
    s += v.x + v.y + v.z + v.w;
    q += v.x * v.x + v.y * v.y + v.z * v.z + v.w * v.w;
  }
#pragma unroll
  for (int off = 32; off > 0; off >>= 1) {
    s += __shfl_down(s, off);
    q += __shfl_down(q, off);
  }
  __shared__ float sh[8];
  const int lane = tid & 63, wid = tid >> 6;
  if (lane == 0) { sh[wid] = s; sh[4 + wid] = q; }
  __syncthreads();
  if (tid == 0) {
    const float S = sh[0] + sh[1] + sh[2] + sh[3];
    const float Q = sh[4] + sh[5] + sh[6] + sh[7];
    const float mean = S * (1.f / 65536.f);
    const float var  = Q * (1.f / 65536.f) - mean * mean;
    stats[bo] = make_float2(mean, __frsqrt_rn(var + 1e-5f));
  }
}

// ---------------------------------------------------------------------------
// Final in-place InstanceNorm + LeakyReLU on d_out.
// ---------------------------------------------------------------------------
__global__ void finalize_kernel(float* __restrict__ y,
                                const float2* __restrict__ stats) {
  const int n4 = (4 * 32 * 65536) / 4;  // 2097152 float4s
  float4* p = reinterpret_cast<float4*>(y);
  for (int i = blockIdx.x * blockDim.x + threadIdx.x; i < n4;
       i += gridDim.x * blockDim.x) {
    float4 v = p[i];
    const float2 st = stats[i >> 14];   // 16384 float4 per plane
    float t;
    t = (v.x - st.x) * st.y; v.x = t < 0.f ? 0.2f * t : t;
    t = (v.y - st.x) * st.y; v.y = t < 0.f ? 0.2f * t : t;
    t = (v.z - st.x) * st.y; v.z = t < 0.f ? 0.2f * t : t;
    t = (v.w - st.x) * st.y; v.w = t < 0.f ? 0.2f * t : t;
    p[i] = v;
  }
}

// ---------------------------------------------------------------------------
extern "C" void kernel_launch(void* const* d_in, const int* in_sizes, int n_in,
                              void* d_out, int out_size, void* d_ws,
                              size_t ws_size, hipStream_t stream) {
  const float* image = (const float*)d_in[0];
  const float* w1    = (const float*)d_in[1];
  const float* w2    = (const float*)d_in[2];
  float* out = (float*)d_out;
  float* ws  = (float*)d_ws;

  // ws layout (floats): kern1[123904] kern2[123904] y1[8388608] stats[512]
  float*  kern1  = ws;
  float*  kern2  = ws + 123904;
  float*  y1     = ws + 247808;
  float2* stats1 = (float2*)(ws + 247808 + 8388608);
  float2* stats2 = stats1 + 128;

  build_kern_kernel<<<64, 128, 0, stream>>>(w1, w2, kern1, kern2);

  dim3 cgrid(8, 16, 4);  // 32x16 tiles, batch; 512 blocks = 2/CU
  conv_kernel<false><<<cgrid, 512, 0, stream>>>(image, kern1, y1, nullptr);
  stats_kernel<<<128, 256, 0, stream>>>(y1, stats1);
  conv_kernel<true><<<cgrid, 512, 0, stream>>>(y1, kern2, out, stats1);
  stats_kernel<<<128, 256, 0, stream>>>(out, stats2);
  finalize_kernel<<<2048, 256, 0, stream>>>(out, stats2);
}